// Round 2
// baseline (387.650 us; speedup 1.0000x reference)
//
#include <hip/hip_runtime.h>

#define NN 8192
#define DD 128

// Kernel 1: proj_i[r] = dot(x[r], w[0:128]) + b ; proj_j[r] = dot(x[r], w[128:256])
// One 64-lane wave per row; lane l handles x[r][2l], x[r][2l+1].
__global__ void proj_kernel(const float* __restrict__ x,
                            const float* __restrict__ w,
                            const float* __restrict__ b,
                            float* __restrict__ proj) {
    int gtid = blockIdx.x * blockDim.x + threadIdx.x;
    int row  = gtid >> 6;          // one wave per row
    int lane = threadIdx.x & 63;
    if (row >= NN) return;

    const float2 xv = *reinterpret_cast<const float2*>(x + (size_t)row * DD + lane * 2);
    const float2 wi = *reinterpret_cast<const float2*>(w + lane * 2);
    const float2 wj = *reinterpret_cast<const float2*>(w + DD + lane * 2);

    float si = xv.x * wi.x + xv.y * wi.y;
    float sj = xv.x * wj.x + xv.y * wj.y;

    #pragma unroll
    for (int off = 32; off > 0; off >>= 1) {
        si += __shfl_xor(si, off, 64);
        sj += __shfl_xor(sj, off, 64);
    }
    if (lane == 0) {
        proj[row]      = si + b[0];   // fold bias into proj_i
        proj[NN + row] = sj;
    }
}

// Kernel 2: out[r][c] = sigmoid(proj_i[r] + proj_j[c]); float4 stores.
__global__ void att_kernel(const float* __restrict__ proj,
                           float4* __restrict__ out) {
    const unsigned cols4 = NN / 4;                 // 2048
    const unsigned total = (unsigned)NN * cols4;   // 16M float4s
    const unsigned stride = gridDim.x * blockDim.x;
    const float4* __restrict__ pj4 = reinterpret_cast<const float4*>(proj + NN);

    for (unsigned idx = blockIdx.x * blockDim.x + threadIdx.x; idx < total; idx += stride) {
        unsigned r  = idx >> 11;     // / 2048
        unsigned c4 = idx & 2047;
        float  pi = proj[r];
        float4 pj = pj4[c4];
        float4 o;
        o.x = 1.0f / (1.0f + __expf(-(pi + pj.x)));
        o.y = 1.0f / (1.0f + __expf(-(pi + pj.y)));
        o.z = 1.0f / (1.0f + __expf(-(pi + pj.z)));
        o.w = 1.0f / (1.0f + __expf(-(pi + pj.w)));
        out[idx] = o;
    }
}

extern "C" void kernel_launch(void* const* d_in, const int* in_sizes, int n_in,
                              void* d_out, int out_size, void* d_ws, size_t ws_size,
                              hipStream_t stream) {
    const float* x = (const float*)d_in[0];
    // d_in[1] = adj — unused by the reference.
    const float* w = (const float*)d_in[2];
    const float* b = (const float*)d_in[3];
    float* proj = (float*)d_ws;          // 2*NN floats = 64 KB
    float* out  = (float*)d_out;

    // Kernel 1: 8192 waves -> 2048 waves of 4 per block (256 threads)
    dim3 b1(256);
    dim3 g1((NN * 64 + 255) / 256);      // 2048 blocks
    proj_kernel<<<g1, b1, 0, stream>>>(x, w, b, proj);

    // Kernel 2: grid-stride over 16M float4, 2048 blocks x 256 threads
    dim3 b2(256);
    dim3 g2(2048);
    att_kernel<<<g2, b2, 0, stream>>>(proj, (float4*)out);
}